// Round 11
// baseline (317.019 us; speedup 1.0000x reference)
//
#include <hip/hip_runtime.h>

// Problem constants
#define EMB 1024
#define NH 16
#define HD 64
#define SEQ 2048
#define BB 4

typedef __attribute__((ext_vector_type(8))) short bf8;   // 8 bf16 (4 VGPRs)
typedef __attribute__((ext_vector_type(4))) short bf4;   // 4 bf16 (2 VGPRs)
typedef __attribute__((ext_vector_type(4))) float f4;    // MFMA C/D frag

#define MFMA16(a, b, c) __builtin_amdgcn_mfma_f32_16x16x32_bf16((a), (b), (c), 0, 0, 0)

#if defined(__has_builtin)
#if __has_builtin(__builtin_amdgcn_mfma_f32_16x16x16_bf16_1k)
#define HAVE_MFMA16X16 1
#endif
#if __has_builtin(__builtin_amdgcn_exp2f)
#define EXP2F __builtin_amdgcn_exp2f
#endif
#if __has_builtin(__builtin_amdgcn_cvt_pk_bf16_f32)
#define HAVE_PK_BF16 1
#endif
#if __has_builtin(__builtin_amdgcn_perm)
#define HAVE_PERM 1
#endif
#endif
#ifndef EXP2F
#define EXP2F exp2f
#endif

__device__ inline f4 pv_mfma(bf4 a, bf4 b, f4 c) {
#ifdef HAVE_MFMA16X16
  return __builtin_amdgcn_mfma_f32_16x16x16_bf16_1k(a, b, c, 0, 0, 0);
#else
  bf8 av, bv;
  *(bf4*)&av = a;  ((int*)&av)[2] = 0; ((int*)&av)[3] = 0;
  *(bf4*)&bv = b;  ((int*)&bv)[2] = 0; ((int*)&bv)[3] = 0;
  return __builtin_amdgcn_mfma_f32_16x16x32_bf16(av, bv, c, 0, 0, 0);
#endif
}

// global -> LDS direct copy, 16B per lane (wave-uniform base + lane*16).
#define GLL16(g, l)                                                     \
  __builtin_amdgcn_global_load_lds(                                     \
      (__attribute__((address_space(1))) void*)(g),                     \
      (__attribute__((address_space(3))) void*)(l), 16, 0, 0)

__device__ inline unsigned short f2bf(float f) {
  union { float f; unsigned u; } v; v.f = f;
  unsigned u = v.u;
  u += 0x7fffu + ((u >> 16) & 1u);   // RNE
  return (unsigned short)(u >> 16);
}

// pack two fp32 -> bf16x2 dword (probabilities: no NaN/Inf).
// Defined-semantics paths only (R7: inline-asm cvt_pk produced NaN).
__device__ inline unsigned pkbf(float a, float b) {
#ifdef HAVE_PK_BF16
  typedef __attribute__((ext_vector_type(2))) __bf16 bf16x2;
  union { bf16x2 v; unsigned u; } c;
  c.v = __builtin_amdgcn_cvt_pk_bf16_f32(a, b);
  return c.u;
#elif defined(HAVE_PERM)
  union { float f; unsigned u; } ua, ub; ua.f = a; ub.f = b;
  return __builtin_amdgcn_perm(ub.u + 0x8000u, ua.u + 0x8000u, 0x07060302u);
#else
  union { float f; unsigned u; } ua, ub; ua.f = a; ub.f = b;
  return ((ua.u + 0x8000u) >> 16) | ((ub.u + 0x8000u) & 0xFFFF0000u);
#endif
}

#define SCALE_LOG2E 0.1803368801111244f  // (1/8) * log2(e)

// ---------------- fp32 -> bf16 convert (memory-bound, all 3 inputs fused) ---
__global__ void cvt_all(const float* __restrict__ x, const float* __restrict__ wq,
                        const float* __restrict__ wo, unsigned short* __restrict__ out) {
  int i = blockIdx.x * blockDim.x + threadIdx.x;
  float4 f;
  if (i < 2097152)      f = ((const float4*)x)[i];
  else if (i < 2883584) f = ((const float4*)wq)[i - 2097152];
  else                  f = ((const float4*)wo)[i - 2883584];
  ushort4 o;
  o.x = f2bf(f.x); o.y = f2bf(f.y); o.z = f2bf(f.z); o.w = f2bf(f.w);
  ((ushort4*)out)[i] = o;
}

// ======================= 8-phase 256x256 QKV GEMM ===========================
// C[8192,3072] = A[8192,1024] x B[3072,1024]^T. BK=64, 512 thr / 8 waves
// (2M x 4N), per-wave C = 128x64 (acc[8][4]). LDS 128KB: 2-dbuf A(256x64) +
// B(256x64), rows 128B, chunk j stored XOR'd by (row&7) (T2 swizzle: linear
// GLL16 dest + pre-swizzled per-lane global src + XOR'd ds_read -> ~conflict-
// free b128). 4 phases/K-tile, 16 MFMA each, quadrant order (m0,n0)(m1,n0)
// (m1,n1)(m0,n1): each phase reads ONE new operand subtile. Staging order
// H1=A{0-63,128-191} H2=B{0-31,64-95,128-159,192-223} H3=A{64-127,192-255}
// H4=B{+32 sets} makes phase p's new data the oldest outstanding pair ->
// counted s_waitcnt vmcnt(4) at ph1-3 (T4: never 0 mid-loop), none at ph4.
// vmcnt-BEFORE-barrier gives cross-wave GLL16 visibility; asm memory fences
// stop the compiler hoisting LDS reads past raw s_barrier. T5 setprio.
#define PSYNC(VMSTR)                                          \
  do {                                                        \
    asm volatile("s_waitcnt " VMSTR ::: "memory");            \
    __builtin_amdgcn_s_barrier();                             \
    asm volatile("" ::: "memory");                            \
  } while (0)
#define PSYNC_NOVM()                                          \
  do {                                                        \
    asm volatile("" ::: "memory");                            \
    __builtin_amdgcn_s_barrier();                             \
    asm volatile("" ::: "memory");                            \
  } while (0)

__global__ __launch_bounds__(512, 2) void gemm_qkv8(
    const unsigned short* __restrict__ A, const unsigned short* __restrict__ B,
    unsigned short* __restrict__ qkb, unsigned short* __restrict__ vtb) {
  __shared__ unsigned short lA[2][256 * 64];   // 64KB
  __shared__ unsigned short lB[2][256 * 64];   // 64KB
  const int K = 1024;

  const int t = threadIdx.x;
  const int lane = t & 63;
  const int w = t >> 6;
  const int quad = lane >> 4;
  const int lcol = lane & 15;
  const int lx7 = lcol & 15 & 7;

  // XCD-chunked swizzle over 384 blocks (12 n-tiles x 32 m-tiles)
  const int flat = blockIdx.x;
  const int sw = (flat & 7) * 48 + (flat >> 3);
  const int m0 = (sw / 12) * 256;
  const int n0 = (sw % 12) * 256;

  const int wm = (w & 1) * 128;
  const int wn = (w >> 1) * 64;

  f4 acc[8][4];
#pragma unroll
  for (int i = 0; i < 8; i++)
#pragma unroll
    for (int j = 0; j < 4; j++) acc[i][j] = (f4){0.f, 0.f, 0.f, 0.f};

  // staging geometry: thread t covers stripe-local row srow, stored chunk t&7,
  // source chunk (t&7)^(srow&7)  (row&7 == srow&7 for all stripe bases, mod 8)
  const int srow = t >> 3;                        // 0..63
  const int schunk = (t & 7) ^ (srow & 7);
  const unsigned short* gA = A + (size_t)(m0 + srow) * K + schunk * 8;
  const int bcol1 = srow + (srow & 32);           // {0..31, 64..95}
  const unsigned short* gB0 = B + (size_t)n0 * K + schunk * 8;

  // H = one half-tile = 2 GLL16/thread
#define STAGE_A(bufi, rb, kt1)                                               \
  do {                                                                       \
    GLL16(gA + (size_t)(rb) * K + (kt1), &lA[bufi][(rb) * 64 + t * 8]);      \
    GLL16(gA + (size_t)((rb) + 128) * K + (kt1),                             \
          &lA[bufi][((rb) + 128) * 64 + t * 8]);                             \
  } while (0)
#define STAGE_B(bufi, cb, kt1)                                               \
  do {                                                                       \
    GLL16(gB0 + (size_t)((cb) + bcol1) * K + (kt1),                          \
          &lB[bufi][((cb) + bcol1) * 64 + (t & 7) * 8]);                     \
    GLL16(gB0 + (size_t)((cb) + bcol1 + 128) * K + (kt1),                    \
          &lB[bufi][((cb) + bcol1 + 128) * 64 + (t & 7) * 8]);               \
  } while (0)

  bf8 af[4][2], bfr[2][2];
#define LOAD_AF(cb, mq)                                                      \
  _Pragma("unroll") for (int i = 0; i < 4; i++) _Pragma("unroll")            \
      for (int kk = 0; kk < 2; kk++)                                         \
          af[i][kk] = *(const bf8*)&lA[cb][(wm + (mq)*64 + i * 16 + lcol) *  \
                                              64 +                          \
                                          (((kk << 2) | quad) ^ lx7) * 8]
#define LOAD_BF(cb, nq)                                                      \
  _Pragma("unroll") for (int j = 0; j < 2; j++) _Pragma("unroll")            \
      for (int kk = 0; kk < 2; kk++)                                         \
          bfr[j][kk] = *(const bf8*)&lB[cb][(wn + (nq)*32 + j * 16 + lcol) * \
                                               64 +                         \
                                           (((kk << 2) | quad) ^ lx7) * 8]
#define MFMA_Q(mq, nq)                                                       \
  do {                                                                       \
    __builtin_amdgcn_s_setprio(1);                                           \
    _Pragma("unroll") for (int i = 0; i < 4; i++) _Pragma("unroll")          \
        for (int j = 0; j < 2; j++) _Pragma("unroll")                        \
            for (int kk = 0; kk < 2; kk++)                                   \
                acc[(mq)*4 + i][(nq)*2 + j] =                                \
                    MFMA16(af[i][kk], bfr[j][kk], acc[(mq)*4 + i][(nq)*2 + j]); \
    __builtin_amdgcn_s_setprio(0);                                           \
  } while (0)

  // prologue: stage K-tile 0 (H1..H4) into buf 0
  STAGE_A(0, 0, 0);
  STAGE_B(0, 0, 0);
  STAGE_A(0, 64, 0);
  STAGE_B(0, 32, 0);

  const int nk = K / 64;   // 16
  for (int kt = 0; kt < nk; ++kt) {
    const int cur = kt & 1;
    const int nxt = cur ^ 1;
    const int k1 = (kt + 1) * 64;
    const bool st = (kt + 1 < nk);

    // ---- ph1: quadrant (m0,n0); new H1(A-m0) + H2(B-n0); stage H1(t+1)
    PSYNC("vmcnt(4)");
    LOAD_AF(cur, 0);
    LOAD_BF(cur, 0);
    if (st) STAGE_A(nxt, 0, k1);
    MFMA_Q(0, 0);

    // ---- ph2: quadrant (m1,n0); new H3(A-m1); B from regs; stage H2(t+1)
    if (st) PSYNC("vmcnt(4)"); else PSYNC("vmcnt(2)");
    LOAD_AF(cur, 1);
    if (st) STAGE_B(nxt, 0, k1);
    MFMA_Q(1, 0);

    // ---- ph3: quadrant (m1,n1); new H4(B-n1); A from regs; stage H3(t+1)
    if (st) PSYNC("vmcnt(4)"); else PSYNC("vmcnt(0)");
    LOAD_BF(cur, 1);
    if (st) STAGE_A(nxt, 64, k1);
    MFMA_Q(1, 1);

    // ---- ph4: quadrant (m0,n1); A-m0 re-read from LDS; stage H4(t+1)
    PSYNC_NOVM();
    LOAD_AF(cur, 0);
    if (st) STAGE_B(nxt, 32, k1);
    MFMA_Q(0, 1);
  }

  // ---- epilogue (n0 is 256-aligned: blocks are pure Q, K, or V) ----
  if (n0 >= 2048) {
#pragma unroll
    for (int MF = 0; MF < 8; MF++) {
#pragma unroll
      for (int NF = 0; NF < 4; NF++) {
        int f = n0 - 2048 + wn + NF * 16 + lcol;       // h*64+d
        int mg = m0 + wm + MF * 16 + quad * 4;         // flat b*2048+s
        int bb = mg >> 11, ss = mg & 2047;
        ushort4 pk;
        pk.x = f2bf(acc[MF][NF][0]); pk.y = f2bf(acc[MF][NF][1]);
        pk.z = f2bf(acc[MF][NF][2]); pk.w = f2bf(acc[MF][NF][3]);
        *(ushort4*)&vtb[((size_t)(bb * 1024 + f)) * 2048 + ss] = pk;
      }
    }
  } else {
    const float scl = (n0 >= 1024) ? SCALE_LOG2E : 1.f;
#pragma unroll
    for (int MF = 0; MF < 8; MF++) {
#pragma unroll
      for (int NF = 0; NF < 4; NF++) {
        int n = n0 + wn + NF * 16 + lcol;
#pragma unroll
        for (int r = 0; r < 4; r++) {
          int m = m0 + wm + MF * 16 + quad * 4 + r;
          qkb[(size_t)m * 2048 + n] = f2bf(acc[MF][NF][r] * scl);
        }
      }
    }
  }
}

// ---------------- BT GEMM (m97 structure) — out-projection only -------------
template <bool OUTF32>
__global__ __launch_bounds__(256, 3) void gemm_bt(
    const unsigned short* __restrict__ A, const unsigned short* __restrict__ B,
    void* __restrict__ Cout, const float* __restrict__ bias,
    unsigned short* __restrict__ vtb,
    int M, int N, int K, int ldC, int nsplit) {
  __shared__ unsigned short la[2][128 * 32];
  __shared__ unsigned short lb[2][128 * 32];

  const int t = threadIdx.x;
  const int lane = t & 63;
  const int w = t >> 6;
  const int quad = lane >> 4;
  const int lcol = lane & 15;

  const int nbx = gridDim.x;
  const int flat = blockIdx.y * nbx + blockIdx.x;
  const int nper = (nbx * gridDim.y) >> 3;
  const int sw = (flat & 7) * nper + (flat >> 3);
  const int m0 = (sw / nbx) * 128;
  const int n0 = (sw % nbx) * 128;

  const int wm = (w & 1) * 64;
  const int wn = (w >> 1) * 64;

  f4 acc[4][4];
#pragma unroll
  for (int i = 0; i < 4; i++)
#pragma unroll
    for (int j = 0; j < 4; j++) acc[i][j] = (f4){0.f, 0.f, 0.f, 0.f};

  const int srow = t >> 2;
  const int scol = (t & 3) * 8;
  const unsigned short* gA = A + (size_t)(m0 + srow) * K + scol;
  const unsigned short* gB = B + (size_t)(n0 + srow) * K + scol;

  GLL16(gA, la[0] + t * 8);
  GLL16(gA + (size_t)64 * K, la[0] + 64 * 32 + t * 8);
  GLL16(gB, lb[0] + t * 8);
  GLL16(gB + (size_t)64 * K, lb[0] + 64 * 32 + t * 8);

  const int nk = K >> 5;
  for (int it = 0; it < nk; ++it) {
    const int cur = it & 1;
    __syncthreads();

    if (it + 1 < nk) {
      const int nxt = cur ^ 1;
      const int kt = (it + 1) << 5;
      GLL16(gA + kt, la[nxt] + t * 8);
      GLL16(gA + kt + (size_t)64 * K, la[nxt] + 64 * 32 + t * 8);
      GLL16(gB + kt, lb[nxt] + t * 8);
      GLL16(gB + kt + (size_t)64 * K, lb[nxt] + 64 * 32 + t * 8);
    }

    bf8 af[4], bfr[4];
#pragma unroll
    for (int i = 0; i < 4; i++) {
      af[i]  = *(const bf8*)&la[cur][(wm + i * 16 + lcol) * 32 + quad * 8];
      bfr[i] = *(const bf8*)&lb[cur][(wn + i * 16 + lcol) * 32 + quad * 8];
    }
#pragma unroll
    for (int i = 0; i < 4; i++)
#pragma unroll
      for (int j = 0; j < 4; j++)
        acc[i][j] = MFMA16(af[i], bfr[j], acc[i][j]);
  }

  if (!OUTF32 && n0 >= nsplit) {
#pragma unroll
    for (int i = 0; i < 4; i++) {
#pragma unroll
      for (int j = 0; j < 4; j++) {
        int f = n0 + wn + j * 16 + lcol - nsplit;
        int mg = m0 + wm + i * 16 + quad * 4;
        int bb = mg >> 11, ss = mg & 2047;
        ushort4 pk;
        pk.x = f2bf(acc[i][j][0]); pk.y = f2bf(acc[i][j][1]);
        pk.z = f2bf(acc[i][j][2]); pk.w = f2bf(acc[i][j][3]);
        *(ushort4*)&vtb[((size_t)(bb * 1024 + f)) * 2048 + ss] = pk;
      }
    }
  } else {
#pragma unroll
    for (int i = 0; i < 4; i++) {
#pragma unroll
      for (int j = 0; j < 4; j++) {
        int n = n0 + wn + j * 16 + lcol;
        const float scl = (!OUTF32 && n >= 1024) ? SCALE_LOG2E : 1.f;
#pragma unroll
        for (int r = 0; r < 4; r++) {
          int m = m0 + wm + i * 16 + quad * 4 + r;
          if (OUTF32) {
            float v = acc[i][j][r] + (bias ? bias[n] : 0.f);
            ((float*)Cout)[(size_t)m * ldC + n] = v;
          } else {
            ((unsigned short*)Cout)[(size_t)m * ldC + n] = f2bf(acc[i][j][r] * scl);
          }
        }
      }
    }
  }
}

// ---------------- flash attention (FROZEN at R9: 131-132us) -----------------
#define BKEEP (-16.0f)
#define BDROP (-1e30f)

__global__ __launch_bounds__(512, 4) void attn_kernel(
    const unsigned short* __restrict__ qk, const unsigned short* __restrict__ vtg,
    const int* __restrict__ mask, unsigned short* __restrict__ outb) {
  __shared__ unsigned short kv[2 * 16384];
  __shared__ __align__(16) float bt[2][128];

  const int t = threadIdx.x;
  const int lane = t & 63;
  const int w = t >> 6;
  const int quad = lane >> 4;
  const int lcol = lane & 15;
  const int lx = lcol & 7;

  const int id = blockIdx.x + (blockIdx.y << 4) + (blockIdx.z << 8);
  const int g  = (id & 7) + ((id >> 7) << 3);
  const int q0 = ((id >> 3) & 15) * 128;
  const int h = g & 15;
  const int b = g >> 4;

  const unsigned short* qbase = qk + (size_t)(b * SEQ) * 2048 + h * HD;
  const unsigned short* kbase = qbase + 1024;
  const unsigned short* vbase = vtg + (size_t)((b * 16 + h) * 64) * SEQ;

  const int qrow = q0 + w * 16 + lcol;
  const bf8 qf0 = *(const bf8*)(qbase + (size_t)qrow * 2048 + quad * 8);
  const bf8 qf1 = *(const bf8*)(qbase + (size_t)qrow * 2048 + 32 + quad * 8);

  f4 o[4];
#pragma unroll
  for (int db = 0; db < 4; db++) o[db] = (f4){0.f, 0.f, 0.f, 0.f};
  float lsum = 0.f;

  const int sr = t >> 3;
  const int sc = ((t & 7) ^ (sr & 7)) * 8;
  const unsigned short* gk = kbase + (size_t)sr * 2048 + sc;
  const int vd = t >> 4;
  const int vc8 = ((t & 15) ^ (vd & 7)) * 8;
  const unsigned short* gv = vbase + (size_t)vd * SEQ + vc8;

  const int NT = SEQ / 128;

  GLL16(gk, kv + t * 8);
  GLL16(gk + (size_t)64 * 2048, kv + 4096 + t * 8);
  GLL16(gv, kv + 8192 + t * 8);
  GLL16(gv + (size_t)32 * SEQ, kv + 12288 + t * 8);
  if (t < 128) bt[0][t] = mask[b * SEQ + t] ? BKEEP : BDROP;
  int pmv = (t < 128) ? mask[b * SEQ + 128 + t] : 0;

  for (int it = 0; it < NT; ++it) {
    const int cur = (it & 1) * 16384;
    __syncthreads();

    if (it + 1 < NT) {
      const int nxt = ((it + 1) & 1) * 16384;
      const size_t k1 = (size_t)(it + 1) * 128;
      GLL16(gk + k1 * 2048, kv + nxt + t * 8);
      GLL16(gk + (k1 + 64) * 2048, kv + nxt + 4096 + t * 8);
      GLL16(gv + k1, kv + nxt + 8192 + t * 8);
      GLL16(gv + (size_t)32 * SEQ + k1, kv + nxt + 12288 + t * 8);
      if (t < 128) bt[(it + 1) & 1][t] = pmv ? BKEEP : BDROP;
      int kn = (it + 2 < NT) ? (it + 2) * 128 : 0;
      pmv = (t < 128) ? mask[b * SEQ + kn + t] : 0;
    }

    const unsigned short* kcur = kv + cur;
    const unsigned short* vcur = kv + cur + 8192;
    const float* bcur = bt[it & 1];

#pragma unroll
    for (int hh = 0; hh < 2; hh++) {
      f4 sT[4];
      __builtin_amdgcn_s_setprio(1);
#pragma unroll
      for (int kb = 0; kb < 4; kb++) {
        const unsigned short* krow = kcur + (hh * 64 + kb * 16 + lcol) * 64;
        bf8 kf0 = *(const bf8*)&krow[(quad ^ lx) * 8];
        bf8 kf1 = *(const bf8*)&krow[((4 + quad) ^ lx) * 8];
        f4 a = *(const f4*)&bcur[hh * 64 + kb * 16 + quad * 4];
        a = MFMA16(kf0, qf0, a);
        a = MFMA16(kf1, qf1, a);
        sT[kb] = a;
      }
      __builtin_amdgcn_s_setprio(0);

      bf4 pfrag[4];
#pragma unroll
      for (int kb = 0; kb < 4; kb++) {
        float p0 = EXP2F(sT[kb][0]);
        float p1 = EXP2F(sT[kb][1]);
        float p2 = EXP2F(sT[kb][2]);
        float p3 = EXP2F(sT[kb][3]);
        lsum += (p0 + p1) + (p2 + p3);
        union { unsigned u[2]; bf4 s; } cv;
        cv.u[0] = pkbf(p0, p1);
        cv.u[1] = pkbf(p2, p3);
        pfrag[kb] = cv.s;
      }

      __builtin_amdgcn_s_setprio(1);
#pragma unroll
      for (int db = 0; db < 4; db++) {
        const unsigned short* vrow = vcur + (db * 16 + lcol) * 128;
#pragma unroll
        for (int kb = 0; kb < 4; kb++) {
          int c = ((hh * 4 + kb) << 1) | (quad >> 1);
          bf4 vf = *(const bf4*)&vrow[(c ^ lx) * 8 + (quad & 1) * 4];
          o[db] = pv_mfma(vf, pfrag[kb], o[db]);
        }
      }
      __builtin_amdgcn_s_setprio(0);
    }
  }

  lsum += __shfl_xor(lsum, 16);
  lsum += __shfl_xor(lsum, 32);
  float inv = 1.f / lsum;
#pragma unroll
  for (int db = 0; db < 4; db++) {
    ushort4 pk;
    pk.x = f2bf(o[db][0] * inv);
    pk.y = f2bf(o[db][1] * inv);
    pk.z = f2bf(o[db][2] * inv);
    pk.w = f2bf(o[db][3] * inv);
    *(ushort4*)&outb[(size_t)(b * SEQ + q0 + w * 16 + lcol) * EMB + h * HD +
                     db * 16 + quad * 4] = pk;
  }
}

extern "C" void kernel_launch(void* const* d_in, const int* in_sizes, int n_in,
                              void* d_out, int out_size, void* d_ws, size_t ws_size,
                              hipStream_t stream) {
  const float* x     = (const float*)d_in[0];
  const float* w_qkv = (const float*)d_in[1];
  const float* w_out = (const float*)d_in[2];
  const float* b_out = (const float*)d_in[3];
  const int*   mask  = (const int*)d_in[4];

  char* ws = (char*)d_ws;
  unsigned short* xb    = (unsigned short*)(ws + 0);          // 16 MB [8192][1024]
  unsigned short* wqkvb = (unsigned short*)(ws + 16777216);   //  6 MB [3072][1024]
  unsigned short* woutb = (unsigned short*)(ws + 23068672);   //  2 MB [1024][1024]
  unsigned short* qkb   = (unsigned short*)(ws + 25165824);   // 32 MB [8192][2048] (Q|K)
  unsigned short* attnb = (unsigned short*)(ws + 58720256);   // 16 MB [8192][1024]
  unsigned short* vtb   = (unsigned short*)(ws + 75497472);   // 16 MB [4096][2048] V^T

  // one fused convert (xb|wqkvb|woutb are contiguous in ws)
  cvt_all<<<12288, 256, 0, stream>>>(x, w_qkv, w_out, (unsigned short*)ws);

  // QKV projection: 8-phase 256^2 kernel. Q,K -> qkb (K pre-scaled); V -> vtb
  gemm_qkv8<<<384, 512, 0, stream>>>(xb, wqkvb, qkb, vtb);

  // attention: 512-thread blocks, 128 q-rows, KVBLK=128, XCD-swizzled
  attn_kernel<<<dim3(16, 16, 4), 512, 0, stream>>>(qkb, vtb, mask, attnb);

  // out projection + bias -> fp32 d_out (m97 structure)
  gemm_bt<true><<<dim3(8, 64), 256, 0, stream>>>(
      attnb, woutb, d_out, b_out, nullptr, 8192, 1024, 1024, 1024, 1 << 30);
}

// Round 12
// 305.050 us; speedup vs baseline: 1.0392x; 1.0392x over previous
//
#include <hip/hip_runtime.h>

// Problem constants
#define EMB 1024
#define NH 16
#define HD 64
#define SEQ 2048
#define BB 4

typedef __attribute__((ext_vector_type(8))) short bf8;   // 8 bf16 (4 VGPRs)
typedef __attribute__((ext_vector_type(4))) short bf4;   // 4 bf16 (2 VGPRs)
typedef __attribute__((ext_vector_type(4))) float f4;    // MFMA C/D frag

#define MFMA16(a, b, c) __builtin_amdgcn_mfma_f32_16x16x32_bf16((a), (b), (c), 0, 0, 0)

#if defined(__has_builtin)
#if __has_builtin(__builtin_amdgcn_mfma_f32_16x16x16_bf16_1k)
#define HAVE_MFMA16X16 1
#endif
#if __has_builtin(__builtin_amdgcn_exp2f)
#define EXP2F __builtin_amdgcn_exp2f
#endif
#if __has_builtin(__builtin_amdgcn_cvt_pk_bf16_f32)
#define HAVE_PK_BF16 1
#endif
#if __has_builtin(__builtin_amdgcn_perm)
#define HAVE_PERM 1
#endif
#endif
#ifndef EXP2F
#define EXP2F exp2f
#endif

__device__ inline f4 pv_mfma(bf4 a, bf4 b, f4 c) {
#ifdef HAVE_MFMA16X16
  return __builtin_amdgcn_mfma_f32_16x16x16_bf16_1k(a, b, c, 0, 0, 0);
#else
  bf8 av, bv;
  *(bf4*)&av = a;  ((int*)&av)[2] = 0; ((int*)&av)[3] = 0;
  *(bf4*)&bv = b;  ((int*)&bv)[2] = 0; ((int*)&bv)[3] = 0;
  return __builtin_amdgcn_mfma_f32_16x16x32_bf16(av, bv, c, 0, 0, 0);
#endif
}

// global -> LDS direct copy, 16B per lane (wave-uniform base + lane*16).
#define GLL16(g, l)                                                     \
  __builtin_amdgcn_global_load_lds(                                     \
      (__attribute__((address_space(1))) void*)(g),                     \
      (__attribute__((address_space(3))) void*)(l), 16, 0, 0)

__device__ inline unsigned short f2bf(float f) {
  union { float f; unsigned u; } v; v.f = f;
  unsigned u = v.u;
  u += 0x7fffu + ((u >> 16) & 1u);   // RNE
  return (unsigned short)(u >> 16);
}

// pack two fp32 -> bf16x2 dword (probabilities: no NaN/Inf).
// Defined-semantics paths only (R7: inline-asm cvt_pk produced NaN).
__device__ inline unsigned pkbf(float a, float b) {
#ifdef HAVE_PK_BF16
  typedef __attribute__((ext_vector_type(2))) __bf16 bf16x2;
  union { bf16x2 v; unsigned u; } c;
  c.v = __builtin_amdgcn_cvt_pk_bf16_f32(a, b);
  return c.u;
#elif defined(HAVE_PERM)
  union { float f; unsigned u; } ua, ub; ua.f = a; ub.f = b;
  return __builtin_amdgcn_perm(ub.u + 0x8000u, ua.u + 0x8000u, 0x07060302u);
#else
  union { float f; unsigned u; } ua, ub; ua.f = a; ub.f = b;
  return ((ua.u + 0x8000u) >> 16) | ((ub.u + 0x8000u) & 0xFFFF0000u);
#endif
}

#define SCALE_LOG2E 0.1803368801111244f  // (1/8) * log2(e)

// ---------------- fp32 -> bf16 convert (memory-bound, all 3 inputs fused) ---
// xb/wqkvb/woutb are CONTIGUOUS in ws -> one output index stream.
// regions (float4 units): x [0,2097152) | w_qkv [..,2883584) | w_out [..,3145728)
__global__ void cvt_all(const float* __restrict__ x, const float* __restrict__ wq,
                        const float* __restrict__ wo, unsigned short* __restrict__ out) {
  int i = blockIdx.x * blockDim.x + threadIdx.x;
  float4 f;
  if (i < 2097152)      f = ((const float4*)x)[i];
  else if (i < 2883584) f = ((const float4*)wq)[i - 2097152];
  else                  f = ((const float4*)wo)[i - 2883584];
  ushort4 o;
  o.x = f2bf(f.x); o.y = f2bf(f.y); o.z = f2bf(f.z); o.w = f2bf(f.w);
  ((ushort4*)out)[i] = o;
}

// ---------------- BT GEMM: C[M,N] = A[M,K] * B[N,K]^T ----------------
// 128x128 tile, BK=32, 256 threads (4 waves). m97 structure. PROVEN BEST
// (R11 post-mortem: the 8-phase 256^2 port regressed QKV ~15us -- schedule
// deviated from m201 on counted-vmcnt placement + ds_read-before-barrier;
// reverted to this verified kernel).
// XCD-chunked block swizzle (m157/m204): contiguous grid chunk per XCD.
// __launch_bounds__(256,3): VGPR cap 170 -> 3 blocks/CU (m97/m114 config).
// Single-barrier double-buffered staging: barrier publishes tile it, GLL16s
// for it+1 go to the other buffer, compute of tile it covers the drain.
// K-columns (n in [1024,2048), !OUTF32) pre-scaled by SCALE_LOG2E.
// Columns n >= nsplit stored TRANSPOSED into vtb[(b*1024 + (n-nsplit))][2048].
template <bool OUTF32>
__global__ __launch_bounds__(256, 3) void gemm_bt(
    const unsigned short* __restrict__ A, const unsigned short* __restrict__ B,
    void* __restrict__ Cout, const float* __restrict__ bias,
    unsigned short* __restrict__ vtb,
    int M, int N, int K, int ldC, int nsplit) {
  __shared__ unsigned short la[2][128 * 32];
  __shared__ unsigned short lb[2][128 * 32];

  const int t = threadIdx.x;
  const int lane = t & 63;
  const int w = t >> 6;
  const int quad = lane >> 4;
  const int lcol = lane & 15;

  // XCD swizzle: flat dispatch id -> chunked id (bijective, grid%8==0)
  const int nbx = gridDim.x;
  const int flat = blockIdx.y * nbx + blockIdx.x;
  const int nper = (nbx * gridDim.y) >> 3;
  const int sw = (flat & 7) * nper + (flat >> 3);
  const int m0 = (sw / nbx) * 128;
  const int n0 = (sw % nbx) * 128;

  const int wm = (w & 1) * 64;
  const int wn = (w >> 1) * 64;

  f4 acc[4][4];
#pragma unroll
  for (int i = 0; i < 4; i++)
#pragma unroll
    for (int j = 0; j < 4; j++) acc[i][j] = (f4){0.f, 0.f, 0.f, 0.f};

  const int srow = t >> 2;
  const int scol = (t & 3) * 8;
  const unsigned short* gA = A + (size_t)(m0 + srow) * K + scol;
  const unsigned short* gB = B + (size_t)(n0 + srow) * K + scol;

  // prologue: stage K-tile 0 into buffer 0
  GLL16(gA, la[0] + t * 8);
  GLL16(gA + (size_t)64 * K, la[0] + 64 * 32 + t * 8);
  GLL16(gB, lb[0] + t * 8);
  GLL16(gB + (size_t)64 * K, lb[0] + 64 * 32 + t * 8);

  const int nk = K >> 5;
  for (int it = 0; it < nk; ++it) {
    const int cur = it & 1;
    __syncthreads();   // publishes tile it (drains GLL16 vmcnt)

    if (it + 1 < nk) {
      const int nxt = cur ^ 1;
      const int kt = (it + 1) << 5;
      GLL16(gA + kt, la[nxt] + t * 8);
      GLL16(gA + kt + (size_t)64 * K, la[nxt] + 64 * 32 + t * 8);
      GLL16(gB + kt, lb[nxt] + t * 8);
      GLL16(gB + kt + (size_t)64 * K, lb[nxt] + 64 * 32 + t * 8);
    }

    bf8 af[4], bfr[4];
#pragma unroll
    for (int i = 0; i < 4; i++) {
      af[i]  = *(const bf8*)&la[cur][(wm + i * 16 + lcol) * 32 + quad * 8];
      bfr[i] = *(const bf8*)&lb[cur][(wn + i * 16 + lcol) * 32 + quad * 8];
    }
#pragma unroll
    for (int i = 0; i < 4; i++)
#pragma unroll
      for (int j = 0; j < 4; j++)
        acc[i][j] = MFMA16(af[i], bfr[j], acc[i][j]);
  }

  if (!OUTF32 && n0 >= nsplit) {
#pragma unroll
    for (int i = 0; i < 4; i++) {
#pragma unroll
      for (int j = 0; j < 4; j++) {
        int f = n0 + wn + j * 16 + lcol - nsplit;      // 0..1023 = h*64+d
        int mg = m0 + wm + i * 16 + quad * 4;          // flat b*2048+s, s%4==0
        int bb = mg >> 11, ss = mg & 2047;
        ushort4 pk;
        pk.x = f2bf(acc[i][j][0]); pk.y = f2bf(acc[i][j][1]);
        pk.z = f2bf(acc[i][j][2]); pk.w = f2bf(acc[i][j][3]);
        *(ushort4*)&vtb[((size_t)(bb * 1024 + f)) * 2048 + ss] = pk;
      }
    }
  } else {
#pragma unroll
    for (int i = 0; i < 4; i++) {
#pragma unroll
      for (int j = 0; j < 4; j++) {
        int n = n0 + wn + j * 16 + lcol;
        // K-columns of the QKV projection carry the softmax scale.
        const float scl = (!OUTF32 && n >= 1024) ? SCALE_LOG2E : 1.f;
#pragma unroll
        for (int r = 0; r < 4; r++) {
          int m = m0 + wm + i * 16 + quad * 4 + r;
          if (OUTF32) {
            float v = acc[i][j][r] + (bias ? bias[n] : 0.f);
            ((float*)Cout)[(size_t)m * ldC + n] = v;
          } else {
            ((unsigned short*)Cout)[(size_t)m * ldC + n] = f2bf(acc[i][j][r] * scl);
          }
        }
      }
    }
  }
}

// ---------------- flash attention (FROZEN at R9: 127-132us) -----------------
// 512 threads / 8 waves, 128 q-rows per block, KVBLK=128 (two 64-key halves
// per barrier reusing sT/pfrag regs), K+V in LDS (66KB, 2 blocks/CU), XCD
// decode keeps all 16 q-tiles of one (b,h) on one XCD (K/V L2-resident:
// FETCH 24.8MB), setprio around MFMA clusters.
// R7 lesson: VGPR budget is the binding box (no doubled per-wave state).
// R8 lesson: V must stay in LDS; K XOR-swizzle is conflict-free.
// Softmax: S' = b + (K*c)Q^T via C-init, p = exp2(S') (c folded into K at
// the GEMM; b = -16 keep / -1e30 drop; 2^-16 cancels in normalization).
#define BKEEP (-16.0f)
#define BDROP (-1e30f)

__global__ __launch_bounds__(512, 4) void attn_kernel(
    const unsigned short* __restrict__ qk, const unsigned short* __restrict__ vtg,
    const int* __restrict__ mask, unsigned short* __restrict__ outb) {
  __shared__ unsigned short kv[2 * 16384];
  __shared__ __align__(16) float bt[2][128];

  const int t = threadIdx.x;
  const int lane = t & 63;
  const int w = t >> 6;
  const int quad = lane >> 4;
  const int lcol = lane & 15;
  const int lx = lcol & 7;

  const int id = blockIdx.x + (blockIdx.y << 4) + (blockIdx.z << 8);
  const int g  = (id & 7) + ((id >> 7) << 3);
  const int q0 = ((id >> 3) & 15) * 128;
  const int h = g & 15;
  const int b = g >> 4;

  const unsigned short* qbase = qk + (size_t)(b * SEQ) * 2048 + h * HD;
  const unsigned short* kbase = qbase + 1024;
  const unsigned short* vbase = vtg + (size_t)((b * 16 + h) * 64) * SEQ;

  const int qrow = q0 + w * 16 + lcol;
  const bf8 qf0 = *(const bf8*)(qbase + (size_t)qrow * 2048 + quad * 8);
  const bf8 qf1 = *(const bf8*)(qbase + (size_t)qrow * 2048 + 32 + quad * 8);

  f4 o[4];
#pragma unroll
  for (int db = 0; db < 4; db++) o[db] = (f4){0.f, 0.f, 0.f, 0.f};
  float lsum = 0.f;

  const int sr = t >> 3;
  const int sc = ((t & 7) ^ (sr & 7)) * 8;
  const unsigned short* gk = kbase + (size_t)sr * 2048 + sc;
  const int vd = t >> 4;
  const int vc8 = ((t & 15) ^ (vd & 7)) * 8;
  const unsigned short* gv = vbase + (size_t)vd * SEQ + vc8;

  const int NT = SEQ / 128;

  GLL16(gk, kv + t * 8);
  GLL16(gk + (size_t)64 * 2048, kv + 4096 + t * 8);
  GLL16(gv, kv + 8192 + t * 8);
  GLL16(gv + (size_t)32 * SEQ, kv + 12288 + t * 8);
  if (t < 128) bt[0][t] = mask[b * SEQ + t] ? BKEEP : BDROP;
  int pmv = (t < 128) ? mask[b * SEQ + 128 + t] : 0;

  for (int it = 0; it < NT; ++it) {
    const int cur = (it & 1) * 16384;
    __syncthreads();

    if (it + 1 < NT) {
      const int nxt = ((it + 1) & 1) * 16384;
      const size_t k1 = (size_t)(it + 1) * 128;
      GLL16(gk + k1 * 2048, kv + nxt + t * 8);
      GLL16(gk + (k1 + 64) * 2048, kv + nxt + 4096 + t * 8);
      GLL16(gv + k1, kv + nxt + 8192 + t * 8);
      GLL16(gv + (size_t)32 * SEQ + k1, kv + nxt + 12288 + t * 8);
      if (t < 128) bt[(it + 1) & 1][t] = pmv ? BKEEP : BDROP;
      int kn = (it + 2 < NT) ? (it + 2) * 128 : 0;
      pmv = (t < 128) ? mask[b * SEQ + kn + t] : 0;
    }

    const unsigned short* kcur = kv + cur;
    const unsigned short* vcur = kv + cur + 8192;
    const float* bcur = bt[it & 1];

#pragma unroll
    for (int hh = 0; hh < 2; hh++) {
      f4 sT[4];
      __builtin_amdgcn_s_setprio(1);
#pragma unroll
      for (int kb = 0; kb < 4; kb++) {
        const unsigned short* krow = kcur + (hh * 64 + kb * 16 + lcol) * 64;
        bf8 kf0 = *(const bf8*)&krow[(quad ^ lx) * 8];
        bf8 kf1 = *(const bf8*)&krow[((4 + quad) ^ lx) * 8];
        f4 a = *(const f4*)&bcur[hh * 64 + kb * 16 + quad * 4];
        a = MFMA16(kf0, qf0, a);
        a = MFMA16(kf1, qf1, a);
        sT[kb] = a;
      }
      __builtin_amdgcn_s_setprio(0);

      bf4 pfrag[4];
#pragma unroll
      for (int kb = 0; kb < 4; kb++) {
        float p0 = EXP2F(sT[kb][0]);
        float p1 = EXP2F(sT[kb][1]);
        float p2 = EXP2F(sT[kb][2]);
        float p3 = EXP2F(sT[kb][3]);
        lsum += (p0 + p1) + (p2 + p3);
        union { unsigned u[2]; bf4 s; } cv;
        cv.u[0] = pkbf(p0, p1);
        cv.u[1] = pkbf(p2, p3);
        pfrag[kb] = cv.s;
      }

      __builtin_amdgcn_s_setprio(1);
#pragma unroll
      for (int db = 0; db < 4; db++) {
        const unsigned short* vrow = vcur + (db * 16 + lcol) * 128;
#pragma unroll
        for (int kb = 0; kb < 4; kb++) {
          int c = ((hh * 4 + kb) << 1) | (quad >> 1);
          bf4 vf = *(const bf4*)&vrow[(c ^ lx) * 8 + (quad & 1) * 4];
          o[db] = pv_mfma(vf, pfrag[kb], o[db]);
        }
      }
      __builtin_amdgcn_s_setprio(0);
    }
  }

  lsum += __shfl_xor(lsum, 16);
  lsum += __shfl_xor(lsum, 32);
  float inv = 1.f / lsum;
#pragma unroll
  for (int db = 0; db < 4; db++) {
    ushort4 pk;
    pk.x = f2bf(o[db][0] * inv);
    pk.y = f2bf(o[db][1] * inv);
    pk.z = f2bf(o[db][2] * inv);
    pk.w = f2bf(o[db][3] * inv);
    *(ushort4*)&outb[(size_t)(b * SEQ + q0 + w * 16 + lcol) * EMB + h * HD +
                     db * 16 + quad * 4] = pk;
  }
}

extern "C" void kernel_launch(void* const* d_in, const int* in_sizes, int n_in,
                              void* d_out, int out_size, void* d_ws, size_t ws_size,
                              hipStream_t stream) {
  const float* x     = (const float*)d_in[0];
  const float* w_qkv = (const float*)d_in[1];
  const float* w_out = (const float*)d_in[2];
  const float* b_out = (const float*)d_in[3];
  const int*   mask  = (const int*)d_in[4];

  char* ws = (char*)d_ws;
  unsigned short* xb    = (unsigned short*)(ws + 0);          // 16 MB [8192][1024]
  unsigned short* wqkvb = (unsigned short*)(ws + 16777216);   //  6 MB [3072][1024]
  unsigned short* woutb = (unsigned short*)(ws + 23068672);   //  2 MB [1024][1024]
  unsigned short* qkb   = (unsigned short*)(ws + 25165824);   // 32 MB [8192][2048] (Q|K)
  unsigned short* attnb = (unsigned short*)(ws + 58720256);   // 16 MB [8192][1024]
  unsigned short* vtb   = (unsigned short*)(ws + 75497472);   // 16 MB [4096][2048] V^T

  // one fused convert (xb|wqkvb|woutb are contiguous in ws)
  cvt_all<<<12288, 256, 0, stream>>>(x, w_qkv, w_out, (unsigned short*)ws);

  // QKV projection: Q,K -> qkb (ld 2048, K pre-scaled); V (n>=2048) -> vtb
  gemm_bt<false><<<dim3(24, 64), 256, 0, stream>>>(
      xb, wqkvb, (void*)qkb, nullptr, vtb, 8192, 3072, 1024, 2048, 2048);

  // attention: 512-thread blocks, 128 q-rows, KVBLK=128, XCD-swizzled
  attn_kernel<<<dim3(16, 16, 4), 512, 0, stream>>>(qkb, vtb, mask, attnb);

  // out projection + bias -> fp32 d_out (m97 structure)
  gemm_bt<true><<<dim3(8, 64), 256, 0, stream>>>(
      attnb, woutb, d_out, b_out, nullptr, 8192, 1024, 1024, 1024, 1 << 30);
}